// Round 8
// baseline (73.543 us; speedup 1.0000x reference)
//
#include <hip/hip_runtime.h>
#include <math.h>

// ThermostatNN: B independent 40-step rollouts of a 2->64->1 MLP plant +
// hysteresis thermostat.
//
// R8: TWO elements per thread (b and b + B/2). Rationale (R4-R7 post-mortem:
// ~440 VALU-issue slots per element-step across four different codegen
// structures, VGPR_Count always < 64 => c[] parked in AGPRs):
//  - any per-use copy cost on SHARED weight values is amortized over 2
//    elements (copies per element-step halve);
//  - per-wave ILP doubles: two independent acc chains + two independent
//    sigmoid chains interleave, hiding VALU dep latency and trans-pipe
//    latency even at 2 waves/SIMD;
//  - weight loads per element-step halve (asm ds_read_b128 broadcast,
//    structurally un-hoistable, conflict-free).
//  Register demand ~200/wave (128 c + 32 transient quads + misc) fits the
//  2-waves/SIMD budget of 256; grid 512 blocks = exactly 2 waves/SIMD.
//
// NUMERICS (do not touch): per-element op sequence identical to R1-R7
// (serial ascending-j single-accumulator dot, expf-based stable sigmoid,
// explicitly rounded updates). absmax == 0.0 in all rounds; a single
// rounding flip in a hysteresis comparison diverges a trajectory by O(100).

#define LHID 64
#define NSTEPS 40

typedef __attribute__((ext_vector_type(4))) float f32x4;

__global__ __launch_bounds__(256, 2) void thermostat_kernel(
    const float* __restrict__ x_init,  // (B,4): step, isOn, temp, aux
    const float* __restrict__ W1,      // (2,64) row-major
    const float* __restrict__ b1,      // (64)
    const float* __restrict__ W2,      // (64,1)
    const float* __restrict__ b2,      // (1)
    float* __restrict__ out,           // (40,B)
    int B)
{
    // LDS: bytes [0,256) = W1 row 0 (a), bytes [256,512) = W2.
    __shared__ __align__(16) float lds_w[2 * LHID];

    int tid = threadIdx.x;
    if (tid < 2 * LHID) {
        lds_w[tid] = (tid < LHID) ? W1[tid] : W2[tid - LHID];
    }
    __syncthreads();

    int half = B >> 1;
    int bA = blockIdx.x * blockDim.x + tid;
    if (bA >= half) return;
    int bB = bA + half;

    float4 stA = reinterpret_cast<const float4*>(x_init)[bA];
    float4 stB = reinterpret_cast<const float4*>(x_init)[bB];
    float isOnA = stA.y, tempA = stA.z, auxA = stA.w;
    float isOnB = stB.y, tempB = stB.z, auxB = stB.w;
    float bias2 = b2[0];

    int n_activeA = (int)fminf(fmaxf((float)NSTEPS - stA.x, 0.0f), (float)NSTEPS);
    int n_activeB = (int)fminf(fmaxf((float)NSTEPS - stB.x, 0.0f), (float)NSTEPS);

    // Per-thread invariant layer-1 partials for both elements.
    float cA[LHID], cB[LHID];
#pragma unroll
    for (int j = 0; j < LHID; j += 4) {
        float4 vr1 = *reinterpret_cast<const float4*>(&W1[LHID + j]);
        float4 vb  = *reinterpret_cast<const float4*>(&b1[j]);
        cA[j+0] = fmaf(auxA, vr1.x, vb.x);
        cA[j+1] = fmaf(auxA, vr1.y, vb.y);
        cA[j+2] = fmaf(auxA, vr1.z, vb.z);
        cA[j+3] = fmaf(auxA, vr1.w, vb.w);
        cB[j+0] = fmaf(auxB, vr1.x, vb.x);
        cB[j+1] = fmaf(auxB, vr1.y, vb.y);
        cB[j+2] = fmaf(auxB, vr1.z, vb.z);
        cB[j+3] = fmaf(auxB, vr1.w, vb.w);
    }

    unsigned lbase = (unsigned)(uintptr_t)(void*)lds_w;

    float* poA = out + bA;
    float* poB = out + bB;

#define LOAD_CHUNK(A0,A1,A2,A3,AW0,AW1,AW2,AW3)                                \
    asm volatile("ds_read_b128 %0, %8 offset:" #A0 "\n\t"                      \
                 "ds_read_b128 %1, %8 offset:" #A1 "\n\t"                      \
                 "ds_read_b128 %2, %8 offset:" #A2 "\n\t"                      \
                 "ds_read_b128 %3, %8 offset:" #A3 "\n\t"                      \
                 "ds_read_b128 %4, %8 offset:" #AW0 "\n\t"                     \
                 "ds_read_b128 %5, %8 offset:" #AW1 "\n\t"                     \
                 "ds_read_b128 %6, %8 offset:" #AW2 "\n\t"                     \
                 "ds_read_b128 %7, %8 offset:" #AW3 "\n\t"                     \
                 "s_waitcnt lgkmcnt(0)"                                        \
                 : "=&v"(qa0), "=&v"(qa1), "=&v"(qa2), "=&v"(qa3),             \
                   "=&v"(qw0), "=&v"(qw1), "=&v"(qw2), "=&v"(qw3)              \
                 : "v"(lbase))

    // One hidden unit for both elements, interleaved (independent chains).
#define UNIT2(AV, WV, J)                                                       \
    {                                                                          \
        float hA = fmaxf(fmaf(tempA, (AV), cA[J]), 0.0f);                      \
        float hB = fmaxf(fmaf(tempB, (AV), cB[J]), 0.0f);                      \
        accA = fmaf(hA, (WV), accA);                                           \
        accB = fmaf(hB, (WV), accB);                                           \
    }

#define CHUNK_MATH(J0)                                                         \
    UNIT2(qa0[0], qw0[0], (J0)+0)  UNIT2(qa0[1], qw0[1], (J0)+1)               \
    UNIT2(qa0[2], qw0[2], (J0)+2)  UNIT2(qa0[3], qw0[3], (J0)+3)               \
    UNIT2(qa1[0], qw1[0], (J0)+4)  UNIT2(qa1[1], qw1[1], (J0)+5)               \
    UNIT2(qa1[2], qw1[2], (J0)+6)  UNIT2(qa1[3], qw1[3], (J0)+7)               \
    UNIT2(qa2[0], qw2[0], (J0)+8)  UNIT2(qa2[1], qw2[1], (J0)+9)               \
    UNIT2(qa2[2], qw2[2], (J0)+10) UNIT2(qa2[3], qw2[3], (J0)+11)              \
    UNIT2(qa3[0], qw3[0], (J0)+12) UNIT2(qa3[1], qw3[1], (J0)+13)              \
    UNIT2(qa3[2], qw3[2], (J0)+14) UNIT2(qa3[3], qw3[3], (J0)+15)

#pragma unroll 1
    for (int t = 0; t < NSTEPS; ++t) {
        float accA = 0.0f, accB = 0.0f;
        {
            f32x4 qa0, qa1, qa2, qa3, qw0, qw1, qw2, qw3;
            LOAD_CHUNK(0, 16, 32, 48, 256, 272, 288, 304);
            CHUNK_MATH(0);
        }
        {
            f32x4 qa0, qa1, qa2, qa3, qw0, qw1, qw2, qw3;
            LOAD_CHUNK(64, 80, 96, 112, 320, 336, 352, 368);
            CHUNK_MATH(16);
        }
        {
            f32x4 qa0, qa1, qa2, qa3, qw0, qw1, qw2, qw3;
            LOAD_CHUNK(128, 144, 160, 176, 384, 400, 416, 432);
            CHUNK_MATH(32);
        }
        {
            f32x4 qa0, qa1, qa2, qa3, qw0, qw1, qw2, qw3;
            LOAD_CHUNK(192, 208, 224, 240, 448, 464, 480, 496);
            CHUNK_MATH(48);
        }

        float xA = __fadd_rn(accA, bias2);
        float xB = __fadd_rn(accB, bias2);

        // stable sigmoid, single exact division (bitwise == two-branch form)
        float eA = expf(-fabsf(xA));
        float eB = expf(-fabsf(xB));
        float numA = (xA >= 0.0f) ? 1.0f : eA;
        float numB = (xB >= 0.0f) ? 1.0f : eB;
        float sA = numA / (1.0f + eA);
        float sB = numB / (1.0f + eB);

        float dtempA = __fmul_rn(__fsub_rn(__fmul_rn(sA, 10.0f), 5.0f), 10.0f);
        float dtempB = __fmul_rn(__fsub_rn(__fmul_rn(sB, 10.0f), 5.0f), 10.0f);

        float tnA_off = __fadd_rn(tempA, dtempA);
        float tnA_on  = __fadd_rn(tnA_off, 5.0f);
        float tnB_off = __fadd_rn(tempB, dtempB);
        float tnB_on  = __fadd_rn(tnB_off, 5.0f);

        bool offA = (isOnA <= 0.5f);
        bool offB = (isOnB <= 0.5f);
        float tempA_new = offA ? tnA_off : tnA_on;
        float tempB_new = offB ? tnB_off : tnB_on;
        float isOnA_new, isOnB_new;
        if (offA) isOnA_new = (tempA_new <= 66.0f) ? 1.0f : isOnA;
        else      isOnA_new = (tempA_new <= 78.0f) ? isOnA : 0.0f;
        if (offB) isOnB_new = (tempB_new <= 66.0f) ? 1.0f : isOnB;
        else      isOnB_new = (tempB_new <= 78.0f) ? isOnB : 0.0f;

        if (t < n_activeA) { tempA = tempA_new; isOnA = isOnA_new; }
        if (t < n_activeB) { tempB = tempB_new; isOnB = isOnB_new; }

        *poA = tempA;
        *poB = tempB;
        poA += B;
        poB += B;
    }
#undef LOAD_CHUNK
#undef UNIT2
#undef CHUNK_MATH
}

extern "C" void kernel_launch(void* const* d_in, const int* in_sizes, int n_in,
                              void* d_out, int out_size, void* d_ws, size_t ws_size,
                              hipStream_t stream) {
    const float* x_init = (const float*)d_in[0];
    const float* W1     = (const float*)d_in[1];
    const float* b1     = (const float*)d_in[2];
    const float* W2     = (const float*)d_in[3];
    const float* b2     = (const float*)d_in[4];
    float* out = (float*)d_out;

    int B = in_sizes[0] / 4;
    int half = B >> 1;
    int threads = 256;
    int blocks = (half + threads - 1) / threads;
    thermostat_kernel<<<blocks, threads, 0, stream>>>(x_init, W1, b1, W2, b2, out, B);
}

// Round 9
// 63.548 us; speedup vs baseline: 1.1573x; 1.1573x over previous
//
#include <hip/hip_runtime.h>
#include <math.h>

// ThermostatNN: B independent 40-step rollouts of a 2->64->1 MLP plant +
// hysteresis thermostat. One thread per batch element.
//
// R9: physical-register endgame. R4-R8 post-mortem: ~410-440 VALU issue
// slots per element-step across FIVE different codegen structures, always
// with VGPR_Count < live-value demand => the allocator parks long-lived
// per-lane arrays in AGPRs (free on split-file gfx90a, NOT on unified-file
// gfx950) and pays v_accvgpr_read per use (~+190/step). Virtual "v"
// constraints and launch bounds cannot forbid that; PHYSICAL constraints can.
//  - c[64] lives in v40..v103, passed to the loop asm as 16 quad operands
//    "{v[40:43]}"... (real operands => live ranges honored; no clobber-holes
//    for compiler temps to corrupt).
//  - Weights in LDS as interleaved pairs (a[j], w2[j]): one broadcast
//    ds_read_b128 covers 2 hidden units. 32 loads/step into scratch
//    v104..v135 (clobbered), double-buffered, counted s_waitcnt lgkmcnt(4)
//    (never drain-to-0 mid-loop). All lanes same address: conflict-free.
//  - Math: v_fma_f32 h, temp, a, c ; v_max_f32 h, 0, h ; v_fmac_f32 acc,
//    h, w2 -- identical ops, identical serial ascending-j order as R1-R8.
//
// NUMERICS (do not touch): absmax == 0.0 vs numpy in all rounds. Serial
// single-accumulator dot, expf-based stable sigmoid, explicitly rounded
// updates. One rounding flip in a hysteresis comparison diverges a
// trajectory by O(100) >> threshold 35.

#define LHID 64
#define NSTEPS 40

typedef __attribute__((ext_vector_type(4))) float f32x4;

// --- pin one c-quad into fixed physical VGPRs -------------------------------
#define PINQ(N0, N1, N2, N3, QV, S0, S1, S2, S3)                               \
    asm volatile("v_mov_b32 v" #N0 ", %1\n\t"                                  \
                 "v_mov_b32 v" #N1 ", %2\n\t"                                  \
                 "v_mov_b32 v" #N2 ", %3\n\t"                                  \
                 "v_mov_b32 v" #N3 ", %4"                                      \
                 : "=&{v[" #N0 ":" #N3 "]}"(QV)                                \
                 : "v"(S0), "v"(S1), "v"(S2), "v"(S3))

// --- loop-asm building blocks ----------------------------------------------
// quad layout from LDS pair-interleave: {a_even, w_even, a_odd, w_odd}
#define QUAD(A0, W0, CE, A1, W1, CO)                                           \
    "v_fma_f32 v136, %1, " A0 ", " CE "\n\t"                                   \
    "v_fma_f32 v137, %1, " A1 ", " CO "\n\t"                                   \
    "v_max_f32 v136, 0, v136\n\t"                                              \
    "v_max_f32 v137, 0, v137\n\t"                                              \
    "v_fmac_f32 %0, v136, " W0 "\n\t"                                          \
    "v_fmac_f32 %0, v137, " W1 "\n\t"

#define GA(C0,C1,C2,C3,C4,C5,C6,C7)                                            \
    QUAD("v104","v105",C0,"v106","v107",C1)                                    \
    QUAD("v108","v109",C2,"v110","v111",C3)                                    \
    QUAD("v112","v113",C4,"v114","v115",C5)                                    \
    QUAD("v116","v117",C6,"v118","v119",C7)

#define GB(C0,C1,C2,C3,C4,C5,C6,C7)                                            \
    QUAD("v120","v121",C0,"v122","v123",C1)                                    \
    QUAD("v124","v125",C2,"v126","v127",C3)                                    \
    QUAD("v128","v129",C4,"v130","v131",C5)                                    \
    QUAD("v132","v133",C6,"v134","v135",C7)

#define LA(O0,O1,O2,O3)                                                        \
    "ds_read_b128 v[104:107], %2 offset:" O0 "\n\t"                            \
    "ds_read_b128 v[108:111], %2 offset:" O1 "\n\t"                            \
    "ds_read_b128 v[112:115], %2 offset:" O2 "\n\t"                            \
    "ds_read_b128 v[116:119], %2 offset:" O3 "\n\t"

#define LB(O0,O1,O2,O3)                                                        \
    "ds_read_b128 v[120:123], %2 offset:" O0 "\n\t"                            \
    "ds_read_b128 v[124:127], %2 offset:" O1 "\n\t"                            \
    "ds_read_b128 v[128:131], %2 offset:" O2 "\n\t"                            \
    "ds_read_b128 v[132:135], %2 offset:" O3 "\n\t"

__global__ __launch_bounds__(256, 1) void thermostat_kernel(
    const float* __restrict__ x_init,  // (B,4): step, isOn, temp, aux
    const float* __restrict__ W1,      // (2,64) row-major
    const float* __restrict__ b1,      // (64)
    const float* __restrict__ W2,      // (64,1)
    const float* __restrict__ b2,      // (1)
    float* __restrict__ out,           // (40,B)
    int B)
{
    // LDS: pair-interleaved weights, lds_w[2j] = W1row0[j], lds_w[2j+1] = W2[j]
    __shared__ __align__(16) float lds_w[2 * LHID];

    int tid = threadIdx.x;
    if (tid < 2 * LHID) {
        lds_w[tid] = (tid & 1) ? W2[tid >> 1] : W1[tid >> 1];
    }
    __syncthreads();

    int b = blockIdx.x * blockDim.x + tid;
    if (b >= B) return;

    float4 st = reinterpret_cast<const float4*>(x_init)[b];
    float step0 = st.x;
    float isOn  = st.y;
    float temp  = st.z;
    float aux   = st.w;
    float bias2 = b2[0];

    int n_active = (int)fminf(fmaxf((float)NSTEPS - step0, 0.0f), (float)NSTEPS);

    // c[j] = aux*W1[1][j] + b1[j]  (exact fmaf, same as all prior rounds)
    float c[LHID];
#pragma unroll
    for (int j = 0; j < LHID; j += 4) {
        float4 vr1 = *reinterpret_cast<const float4*>(&W1[LHID + j]);
        float4 vb  = *reinterpret_cast<const float4*>(&b1[j]);
        c[j+0] = fmaf(aux, vr1.x, vb.x);
        c[j+1] = fmaf(aux, vr1.y, vb.y);
        c[j+2] = fmaf(aux, vr1.z, vb.z);
        c[j+3] = fmaf(aux, vr1.w, vb.w);
    }

    // Pin c into v40..v103 (bit-preserving v_mov; physical regs can never be
    // AGPR-parked or rematerialized).
    f32x4 cq0, cq1, cq2, cq3, cq4, cq5, cq6, cq7;
    f32x4 cq8, cq9, cq10, cq11, cq12, cq13, cq14, cq15;
    PINQ(40,41,42,43,    cq0,  c[0],  c[1],  c[2],  c[3]);
    PINQ(44,45,46,47,    cq1,  c[4],  c[5],  c[6],  c[7]);
    PINQ(48,49,50,51,    cq2,  c[8],  c[9],  c[10], c[11]);
    PINQ(52,53,54,55,    cq3,  c[12], c[13], c[14], c[15]);
    PINQ(56,57,58,59,    cq4,  c[16], c[17], c[18], c[19]);
    PINQ(60,61,62,63,    cq5,  c[20], c[21], c[22], c[23]);
    PINQ(64,65,66,67,    cq6,  c[24], c[25], c[26], c[27]);
    PINQ(68,69,70,71,    cq7,  c[28], c[29], c[30], c[31]);
    PINQ(72,73,74,75,    cq8,  c[32], c[33], c[34], c[35]);
    PINQ(76,77,78,79,    cq9,  c[36], c[37], c[38], c[39]);
    PINQ(80,81,82,83,    cq10, c[40], c[41], c[42], c[43]);
    PINQ(84,85,86,87,    cq11, c[44], c[45], c[46], c[47]);
    PINQ(88,89,90,91,    cq12, c[48], c[49], c[50], c[51]);
    PINQ(92,93,94,95,    cq13, c[52], c[53], c[54], c[55]);
    PINQ(96,97,98,99,    cq14, c[56], c[57], c[58], c[59]);
    PINQ(100,101,102,103,cq15, c[60], c[61], c[62], c[63]);

    unsigned lbase = (unsigned)(uintptr_t)(void*)lds_w;
    float* po = out + b;

#pragma unroll 1
    for (int t = 0; t < NSTEPS; ++t) {
        float acc = 0.0f;
        // 64-unit dot product, fully scheduled by hand:
        // 32 broadcast ds_read_b128 (pairs), double-buffered A/B scratch,
        // counted lgkmcnt(4); 192 VALU in exact serial ascending-j order.
        asm volatile(
            LA("0","16","32","48")
            LB("64","80","96","112")
            "s_waitcnt lgkmcnt(4)\n\t"
            GA("v40","v41","v42","v43","v44","v45","v46","v47")
            LA("128","144","160","176")
            "s_waitcnt lgkmcnt(4)\n\t"
            GB("v48","v49","v50","v51","v52","v53","v54","v55")
            LB("192","208","224","240")
            "s_waitcnt lgkmcnt(4)\n\t"
            GA("v56","v57","v58","v59","v60","v61","v62","v63")
            LA("256","272","288","304")
            "s_waitcnt lgkmcnt(4)\n\t"
            GB("v64","v65","v66","v67","v68","v69","v70","v71")
            LB("320","336","352","368")
            "s_waitcnt lgkmcnt(4)\n\t"
            GA("v72","v73","v74","v75","v76","v77","v78","v79")
            LA("384","400","416","432")
            "s_waitcnt lgkmcnt(4)\n\t"
            GB("v80","v81","v82","v83","v84","v85","v86","v87")
            LB("448","464","480","496")
            "s_waitcnt lgkmcnt(4)\n\t"
            GA("v88","v89","v90","v91","v92","v93","v94","v95")
            "s_waitcnt lgkmcnt(0)\n\t"
            GB("v96","v97","v98","v99","v100","v101","v102","v103")
            : "+v"(acc)
            : "v"(temp), "v"(lbase),
              "{v[40:43]}"(cq0),   "{v[44:47]}"(cq1),
              "{v[48:51]}"(cq2),   "{v[52:55]}"(cq3),
              "{v[56:59]}"(cq4),   "{v[60:63]}"(cq5),
              "{v[64:67]}"(cq6),   "{v[68:71]}"(cq7),
              "{v[72:75]}"(cq8),   "{v[76:79]}"(cq9),
              "{v[80:83]}"(cq10),  "{v[84:87]}"(cq11),
              "{v[88:91]}"(cq12),  "{v[92:95]}"(cq13),
              "{v[96:99]}"(cq14),  "{v[100:103]}"(cq15)
            : "v104","v105","v106","v107","v108","v109","v110","v111",
              "v112","v113","v114","v115","v116","v117","v118","v119",
              "v120","v121","v122","v123","v124","v125","v126","v127",
              "v128","v129","v130","v131","v132","v133","v134","v135",
              "v136","v137");

        float x = __fadd_rn(acc, bias2);

        // stable sigmoid, single exact division (bitwise == two-branch form)
        float e = expf(-fabsf(x));
        float num = (x >= 0.0f) ? 1.0f : e;
        float s = num / (1.0f + e);

        // plant = s*10 - 5 ; dtemp = plant*10
        float plant = __fsub_rn(__fmul_rn(s, 10.0f), 5.0f);
        float dtemp = __fmul_rn(plant, 10.0f);

        float tn_off = __fadd_rn(temp, dtemp);
        float tn_on  = __fadd_rn(tn_off, 5.0f);

        bool off = (isOn <= 0.5f);
        float temp_new = off ? tn_off : tn_on;
        float isOn_new;
        if (off) isOn_new = (temp_new <= 66.0f) ? 1.0f : isOn;
        else     isOn_new = (temp_new <= 78.0f) ? isOn : 0.0f;

        if (t < n_active) {
            temp = temp_new;
            isOn = isOn_new;
        }

        *po = temp;
        po += B;
    }
}

extern "C" void kernel_launch(void* const* d_in, const int* in_sizes, int n_in,
                              void* d_out, int out_size, void* d_ws, size_t ws_size,
                              hipStream_t stream) {
    const float* x_init = (const float*)d_in[0];
    const float* W1     = (const float*)d_in[1];
    const float* b1     = (const float*)d_in[2];
    const float* W2     = (const float*)d_in[3];
    const float* b2     = (const float*)d_in[4];
    float* out = (float*)d_out;

    int B = in_sizes[0] / 4;
    int threads = 256;
    int blocks = (B + threads - 1) / threads;
    thermostat_kernel<<<blocks, threads, 0, stream>>>(x_init, W1, b1, W2, b2, out, B);
}